// Round 1
// 271.162 us; speedup vs baseline: 1.1263x; 1.1263x over previous
//
#include <hip/hip_runtime.h>

// ROIPooler (FPN multi-level ROIAlign, aligned=true), float32 in/out.
// R6: all-fast-path + async global->LDS staging.
//  - NC=4 channels/block, CAPP=1091 window slot: max possible sample window
//    (~1026 floats; span<28 at every level boundary, extreme-aspect lvl2
//    ~114x9) fits -> scattered-gather fallback is dead code (kept for safety).
//  - Staging via __builtin_amdgcn_global_load_lds: flat window index, all 64
//    lanes per instruction, per-lane global addr, uniform LDS base + lane*4.
//    Fire-and-forget; single vmcnt drain at the barrier instead of ~20
//    serialized load->ds_write round trips.
//  - t==ci*49+bin identity for t<196 -> compute writes straight to global,
//    no s_out buffer, 2 barriers total.
// LDS ~17.9KB -> 8 blocks/CU. Grid 512 x 64 blocks of 256.

#define OUTD 7
#define SRD  2
#define SD   14      // OUT*SR samples per axis
#define CCH  256
#define NBOX 256
#define NC   4       // channels per block
#define NCHK (CCH / NC)   // 64 chunks
#define CAPP 1091    // floats per channel slot (odd; >= LMAX + 63 pad)
#define LMAX (CAPP - 63)  // 1028: max stageable window floats
#define NBIN (OUTD * OUTD)

typedef __attribute__((address_space(1))) unsigned int gu32;
typedef __attribute__((address_space(3))) unsigned int lu32;

__device__ __forceinline__ void gl2lds(const float* g, float* l) {
    // 4B per lane: LDS dst = uniform base + lane*4, global src per-lane.
    __builtin_amdgcn_global_load_lds((gu32*)(unsigned long long)g, (lu32*)l, 4, 0, 0);
}

__global__ __launch_bounds__(256) void roi_direct(
    const float* __restrict__ f0, const float* __restrict__ f1,
    const float* __restrict__ f2, const float* __restrict__ f3,
    const float* __restrict__ boxes, float* __restrict__ out)
{
    const int roi = blockIdx.x;
    const int c0  = blockIdx.y * NC;
    const int t   = threadIdx.x;
    const int b   = roi / NBOX;

    const float bx1 = boxes[roi * 4 + 0];
    const float by1 = boxes[roi * 4 + 1];
    const float bx2 = boxes[roi * 4 + 2];
    const float by2 = boxes[roi * 4 + 3];

    // Level assignment (block-uniform).
    const float area = (bx2 - bx1) * (by2 - by1);
    const float sz   = sqrtf(area);
    int lvl = (int)floorf(4.0f + log2f(sz * (1.0f / 224.0f) + 1e-8f));
    lvl = min(max(lvl, 2), 5) - 2;

    const int   wsh   = 8 - lvl;          // log2(W), W = H
    const int   H     = 1 << wsh;
    const int   W     = H;
    const float scale = 1.0f / (float)(4 << lvl);
    const size_t HW   = (size_t)1 << (2 * wsh);

    const float* f  = (lvl == 0) ? f0 : (lvl == 1) ? f1 : (lvl == 2) ? f2 : f3;
    const float* fb = f + (size_t)b * CCH * HW;

    __shared__ int   s_ax0[SD], s_ax1[SD], s_ay0[SD], s_ay1[SD];
    __shared__ float s_wxh[SD], s_wxl[SD], s_wyh[SD], s_wyl[SD];
    __shared__ float s_win[NC * CAPP];   // 17456 B

    if (t < SD) {
        const int i = t;
        const float x1r = bx1 * scale - 0.5f;
        const float y1r = by1 * scale - 0.5f;
        const float x2r = bx2 * scale - 0.5f;
        const float y2r = by2 * scale - 0.5f;
        const float bw = (x2r - x1r) * (1.0f / OUTD);
        const float bh = (y2r - y1r) * (1.0f / OUTD);
        const float g  = ((float)i + 0.5f) * (1.0f / SRD);
        const float ys = y1r + g * bh;
        const float xs = x1r + g * bw;
        const float vy = ((ys >= -1.0f) && (ys <= (float)H)) ? 1.0f : 0.0f;
        const float vx = ((xs >= -1.0f) && (xs <= (float)W)) ? 1.0f : 0.0f;
        const float yc = fminf(fmaxf(ys, 0.0f), (float)(H - 1));
        const float xc = fminf(fmaxf(xs, 0.0f), (float)(W - 1));
        const int y0 = (int)yc;
        const int x0 = (int)xc;
        const float ly = yc - (float)y0;
        const float lx = xc - (float)x0;
        s_ay0[i] = y0;
        s_ay1[i] = min(y0 + 1, H - 1);
        s_ax0[i] = x0;
        s_ax1[i] = min(x0 + 1, W - 1);
        s_wyh[i] = vy * (1.0f - ly);
        s_wyl[i] = vy * ly;
        s_wxh[i] = vx * (1.0f - lx);
        s_wxl[i] = vx * lx;
    }
    __syncthreads();

    // Window bounds (uniform across block; broadcast LDS reads).
    int x_lo = s_ax0[0], x_hi = s_ax1[0], y_lo = s_ay0[0], y_hi = s_ay1[0];
    #pragma unroll
    for (int j = 1; j < SD; ++j) {
        x_lo = min(x_lo, s_ax0[j]); x_hi = max(x_hi, s_ax1[j]);
        y_lo = min(y_lo, s_ay0[j]); y_hi = max(y_hi, s_ay1[j]);
    }
    const int Ww = x_hi - x_lo + 1;
    const int Hw = y_hi - y_lo + 1;
    const int L  = Hw * Ww;

    // Thread -> (channel, bin): identity map t = ci*49 + bin for t < 196.
    const int ci  = t / NBIN;
    const int bin = t - ci * NBIN;
    const int oy  = bin / 7;
    const int ox  = bin - oy * 7;
    const int ia = 2 * oy, ib = ia + 1;
    const int ja = 2 * ox, jb = ja + 1;

    float* ob = out + (size_t)roi * (CCH * NBIN) + (size_t)c0 * NBIN;

    if (L <= LMAX) {
        // -------- fast path (now: all realizable windows) --------
        // Async flat staging: per channel, window floats 0..L-1 laid out
        // contiguously in LDS; each wave DMA's 64 consecutive floats per
        // instruction. o -> (y,x) via float-reciprocal division + fixup.
        const float inv = 1.0f / (float)Ww;
        const int wv = t >> 6, ln = t & 63;
        const int ub = (y_lo << wsh) + x_lo;
        for (int c = 0; c < NC; ++c) {
            const float* cb = fb + (size_t)(c0 + c) * HW + ub;
            float* lb = s_win + c * CAPP;
            for (int o0 = wv * 64; o0 < L; o0 += 256) {
                int o = min(o0 + ln, L - 1);      // tail lanes: dup loads into pad
                int y = (int)((float)o * inv);
                int x = o - y * Ww;
                if (x < 0)   { x += Ww; --y; }
                if (x >= Ww) { x -= Ww; ++y; }
                gl2lds(cb + (y << wsh) + x, lb + o0);
            }
        }
        __syncthreads();   // drains vmcnt -> all DMA landed

        if (t < NC * NBIN) {
            const int ryA0 = (s_ay0[ia] - y_lo) * Ww, ryA1 = (s_ay1[ia] - y_lo) * Ww;
            const int ryB0 = (s_ay0[ib] - y_lo) * Ww, ryB1 = (s_ay1[ib] - y_lo) * Ww;
            const int rxA0 = s_ax0[ja] - x_lo,        rxA1 = s_ax1[ja] - x_lo;
            const int rxB0 = s_ax0[jb] - x_lo,        rxB1 = s_ax1[jb] - x_lo;
            const float wyAh = s_wyh[ia], wyAl = s_wyl[ia];
            const float wyBh = s_wyh[ib], wyBl = s_wyl[ib];
            const float wxAh = s_wxh[ja], wxAl = s_wxl[ja];
            const float wxBh = s_wxh[jb], wxBl = s_wxl[jb];
            const float* w = s_win + ci * CAPP;
            const float acc =
                wyAh * (wxAh * w[ryA0 + rxA0] + wxAl * w[ryA0 + rxA1])
              + wyAl * (wxAh * w[ryA1 + rxA0] + wxAl * w[ryA1 + rxA1])
              + wyAh * (wxBh * w[ryA0 + rxB0] + wxBl * w[ryA0 + rxB1])
              + wyAl * (wxBh * w[ryA1 + rxB0] + wxBl * w[ryA1 + rxB1])
              + wyBh * (wxAh * w[ryB0 + rxA0] + wxAl * w[ryB0 + rxA1])
              + wyBl * (wxAh * w[ryB1 + rxA0] + wxAl * w[ryB1 + rxA1])
              + wyBh * (wxBh * w[ryB0 + rxB0] + wxBl * w[ryB0 + rxB1])
              + wyBl * (wxBh * w[ryB1 + rxB0] + wxBl * w[ryB1 + rxB1]);
            ob[t] = acc * 0.25f;   // coalesced 196-float store
        }
    } else {
        // -------- safety fallback: direct global gather (should be dead) ----
        if (t < NC * NBIN) {
            const float* fc = fb + (size_t)(c0 + ci) * HW;
            const float acc =
                s_wyh[ia] * (s_wxh[ja] * fc[s_ay0[ia] * W + s_ax0[ja]] + s_wxl[ja] * fc[s_ay0[ia] * W + s_ax1[ja]])
              + s_wyl[ia] * (s_wxh[ja] * fc[s_ay1[ia] * W + s_ax0[ja]] + s_wxl[ja] * fc[s_ay1[ia] * W + s_ax1[ja]])
              + s_wyh[ia] * (s_wxh[jb] * fc[s_ay0[ia] * W + s_ax0[jb]] + s_wxl[jb] * fc[s_ay0[ia] * W + s_ax1[jb]])
              + s_wyl[ia] * (s_wxh[jb] * fc[s_ay1[ia] * W + s_ax0[jb]] + s_wxl[jb] * fc[s_ay1[ia] * W + s_ax1[jb]])
              + s_wyh[ib] * (s_wxh[ja] * fc[s_ay0[ib] * W + s_ax0[ja]] + s_wxl[ja] * fc[s_ay0[ib] * W + s_ax1[ja]])
              + s_wyl[ib] * (s_wxh[ja] * fc[s_ay1[ib] * W + s_ax0[ja]] + s_wxl[ja] * fc[s_ay1[ib] * W + s_ax1[ja]])
              + s_wyh[ib] * (s_wxh[jb] * fc[s_ay0[ib] * W + s_ax0[jb]] + s_wxl[jb] * fc[s_ay0[ib] * W + s_ax1[jb]])
              + s_wyl[ib] * (s_wxh[jb] * fc[s_ay1[ib] * W + s_ax0[jb]] + s_wxl[jb] * fc[s_ay1[ib] * W + s_ax1[jb]]);
            ob[t] = acc * 0.25f;
        }
    }
}

extern "C" void kernel_launch(void* const* d_in, const int* in_sizes, int n_in,
                              void* d_out, int out_size, void* d_ws, size_t ws_size,
                              hipStream_t stream) {
    const float* f0    = (const float*)d_in[0];
    const float* f1    = (const float*)d_in[1];
    const float* f2    = (const float*)d_in[2];
    const float* f3    = (const float*)d_in[3];
    const float* boxes = (const float*)d_in[4];
    float*       outp  = (float*)d_out;

    const int R = out_size / (CCH * NBIN);   // 512
    roi_direct<<<dim3(R, NCHK), 256, 0, stream>>>(f0, f1, f2, f3, boxes, outp);
}

// Round 2
// 263.617 us; speedup vs baseline: 1.1586x; 1.0286x over previous
//
#include <hip/hip_runtime.h>

// ROIPooler (FPN multi-level ROIAlign, aligned=true), float32 in/out.
// R7: 16B-wide async staging + monotone-bounds prologue.
//  - global_load_lds width=16: window staged as flat 16B units; window left
//    edge aligned to 4 floats (W is pow2 -> every source row start stays
//    16B-aligned). 4x fewer DMA instructions and 4x less address math vs R6.
//  - Exec-masked tail (u < L4): no LDS pad slop -> 345-unit channel slots,
//    LDS 22528B -> 7 blocks/CU.
//  - Sample coords are monotone -> window bounds = first/last entries; the
//    13-iter min/max loop (52 VALU x 256 thr) is gone.
//  - Per-(wave,channel) rotated staging start balances DMA issue.
// Grid 512 x 64 blocks of 256, 2 barriers/block.

#define OUTD 7
#define SRD  2
#define SD   14      // OUT*SR samples per axis
#define CCH  256
#define NBOX 256
#define NC   4       // channels per block
#define NCHK (CCH / NC)   // 64 chunks
#define CAPU 345     // 16B units per channel slot (= capacity guard)
#define CAPF (CAPU * 4)   // 1380 floats; stride 5520B (16B-aligned, mod32=4)
#define NBIN (OUTD * OUTD)

typedef __attribute__((address_space(1))) unsigned int gu32;
typedef __attribute__((address_space(3))) unsigned int lu32;

__device__ __forceinline__ void gl2lds16(const float* g, float* l) {
    // 16B per lane: LDS dst = uniform base + lane*16, global src per-lane.
    __builtin_amdgcn_global_load_lds((gu32*)(unsigned long long)g, (lu32*)l, 16, 0, 0);
}

__global__ __launch_bounds__(256) void roi_direct(
    const float* __restrict__ f0, const float* __restrict__ f1,
    const float* __restrict__ f2, const float* __restrict__ f3,
    const float* __restrict__ boxes, float* __restrict__ out)
{
    const int roi = blockIdx.x;
    const int c0  = blockIdx.y * NC;
    const int t   = threadIdx.x;
    const int b   = roi / NBOX;

    const float bx1 = boxes[roi * 4 + 0];
    const float by1 = boxes[roi * 4 + 1];
    const float bx2 = boxes[roi * 4 + 2];
    const float by2 = boxes[roi * 4 + 3];

    // Level assignment (block-uniform).
    const float area = (bx2 - bx1) * (by2 - by1);
    const float sz   = sqrtf(area);
    int lvl = (int)floorf(4.0f + log2f(sz * (1.0f / 224.0f) + 1e-8f));
    lvl = min(max(lvl, 2), 5) - 2;

    const int   wsh   = 8 - lvl;          // log2(W), W = H
    const int   H     = 1 << wsh;
    const int   W     = H;
    const float scale = 1.0f / (float)(4 << lvl);
    const size_t HW   = (size_t)1 << (2 * wsh);

    const float* f  = (lvl == 0) ? f0 : (lvl == 1) ? f1 : (lvl == 2) ? f2 : f3;
    const float* fb = f + (size_t)b * CCH * HW;

    __shared__ int   s_ax0[SD], s_ax1[SD], s_ay0[SD], s_ay1[SD];
    __shared__ float s_wxh[SD], s_wxl[SD], s_wyh[SD], s_wyl[SD];
    __shared__ __align__(16) float s_win[NC * CAPF];   // 22080 B

    if (t < SD) {
        const int i = t;
        const float x1r = bx1 * scale - 0.5f;
        const float y1r = by1 * scale - 0.5f;
        const float x2r = bx2 * scale - 0.5f;
        const float y2r = by2 * scale - 0.5f;
        const float bw = (x2r - x1r) * (1.0f / OUTD);
        const float bh = (y2r - y1r) * (1.0f / OUTD);
        const float g  = ((float)i + 0.5f) * (1.0f / SRD);
        const float ys = y1r + g * bh;
        const float xs = x1r + g * bw;
        const float vy = ((ys >= -1.0f) && (ys <= (float)H)) ? 1.0f : 0.0f;
        const float vx = ((xs >= -1.0f) && (xs <= (float)W)) ? 1.0f : 0.0f;
        const float yc = fminf(fmaxf(ys, 0.0f), (float)(H - 1));
        const float xc = fminf(fmaxf(xs, 0.0f), (float)(W - 1));
        const int y0 = (int)yc;
        const int x0 = (int)xc;
        const float ly = yc - (float)y0;
        const float lx = xc - (float)x0;
        s_ay0[i] = y0;
        s_ay1[i] = min(y0 + 1, H - 1);
        s_ax0[i] = x0;
        s_ax1[i] = min(x0 + 1, W - 1);
        s_wyh[i] = vy * (1.0f - ly);
        s_wyl[i] = vy * ly;
        s_wxh[i] = vx * (1.0f - lx);
        s_wxl[i] = vx * lx;
    }
    __syncthreads();

    // Window bounds: samples are monotone -> first/last entries (broadcast).
    const int y_lo = s_ay0[0];
    const int y_hi = s_ay1[SD - 1];
    const int x_lo = s_ax0[0] & ~3;       // align left edge to 16B in source
    const int x_hi = s_ax1[SD - 1];
    const int W4 = (x_hi - x_lo + 4) >> 2;   // padded row width, 16B units
    const int Hw = y_hi - y_lo + 1;
    const int L4 = Hw * W4;                  // window size, 16B units

    // Thread -> (channel, bin): identity map t = ci*49 + bin for t < 196.
    const int ci  = t / NBIN;
    const int bin = t - ci * NBIN;
    const int oy  = bin / 7;
    const int ox  = bin - oy * 7;
    const int ia = 2 * oy, ib = ia + 1;
    const int ja = 2 * ox, jb = ja + 1;

    float* ob = out + (size_t)roi * (CCH * NBIN) + (size_t)c0 * NBIN;

    if (L4 <= CAPU) {
        // -------- fast path (all realizable windows) --------
        const float invW4 = 1.0f / (float)W4;
        const int wv = t >> 6, ln = t & 63;
        const unsigned int gmax = (512u << (2 * wsh)) - 4u;  // tensor floats - 4
        const unsigned int wbase = ((unsigned int)y_lo << wsh) + (unsigned int)x_lo;
        for (int c = 0; c < NC; ++c) {
            const unsigned int ch_base =
                (((unsigned int)(b * CCH + c0 + c)) << (2 * wsh)) + wbase;
            float* lb = s_win + c * CAPF;
            for (int o0 = ((wv + c) & 3) << 6; o0 < L4; o0 += 256) {
                const int u = o0 + ln;
                if (u < L4) {                       // exec-masked tail
                    int y  = (int)((float)u * invW4);
                    int x4 = u - y * W4;
                    if (x4 < 0)        { x4 += W4; --y; }
                    else if (x4 >= W4) { x4 -= W4; ++y; }
                    unsigned int g = ch_base + ((unsigned int)y << wsh) + ((unsigned int)x4 << 2);
                    g = min(g, gmax);               // tensor-end clamp (pad cols)
                    gl2lds16(f + g, lb + (o0 << 2));
                }
            }
        }
        __syncthreads();   // drains vmcnt -> all DMA landed

        if (t < NC * NBIN) {
            const int rs = W4 << 2;   // LDS row stride in floats
            const int ryA0 = (s_ay0[ia] - y_lo) * rs, ryA1 = (s_ay1[ia] - y_lo) * rs;
            const int ryB0 = (s_ay0[ib] - y_lo) * rs, ryB1 = (s_ay1[ib] - y_lo) * rs;
            const int rxA0 = s_ax0[ja] - x_lo,        rxA1 = s_ax1[ja] - x_lo;
            const int rxB0 = s_ax0[jb] - x_lo,        rxB1 = s_ax1[jb] - x_lo;
            const float wyAh = s_wyh[ia], wyAl = s_wyl[ia];
            const float wyBh = s_wyh[ib], wyBl = s_wyl[ib];
            const float wxAh = s_wxh[ja], wxAl = s_wxl[ja];
            const float wxBh = s_wxh[jb], wxBl = s_wxl[jb];
            const float* w = s_win + ci * CAPF;
            const float acc =
                wyAh * (wxAh * w[ryA0 + rxA0] + wxAl * w[ryA0 + rxA1])
              + wyAl * (wxAh * w[ryA1 + rxA0] + wxAl * w[ryA1 + rxA1])
              + wyAh * (wxBh * w[ryA0 + rxB0] + wxBl * w[ryA0 + rxB1])
              + wyAl * (wxBh * w[ryA1 + rxB0] + wxBl * w[ryA1 + rxB1])
              + wyBh * (wxAh * w[ryB0 + rxA0] + wxAl * w[ryB0 + rxA1])
              + wyBl * (wxAh * w[ryB1 + rxA0] + wxAl * w[ryB1 + rxA1])
              + wyBh * (wxBh * w[ryB0 + rxB0] + wxBl * w[ryB0 + rxB1])
              + wyBl * (wxBh * w[ryB1 + rxB0] + wxBl * w[ryB1 + rxB1]);
            ob[t] = acc * 0.25f;   // coalesced 196-float store
        }
    } else {
        // -------- safety fallback: direct global gather (should be dead) ----
        if (t < NC * NBIN) {
            const float* fc = fb + (size_t)(c0 + ci) * HW;
            const float acc =
                s_wyh[ia] * (s_wxh[ja] * fc[s_ay0[ia] * W + s_ax0[ja]] + s_wxl[ja] * fc[s_ay0[ia] * W + s_ax1[ja]])
              + s_wyl[ia] * (s_wxh[ja] * fc[s_ay1[ia] * W + s_ax0[ja]] + s_wxl[ja] * fc[s_ay1[ia] * W + s_ax1[ja]])
              + s_wyh[ia] * (s_wxh[jb] * fc[s_ay0[ia] * W + s_ax0[jb]] + s_wxl[jb] * fc[s_ay0[ia] * W + s_ax1[jb]])
              + s_wyl[ia] * (s_wxh[jb] * fc[s_ay1[ia] * W + s_ax0[jb]] + s_wxl[jb] * fc[s_ay1[ia] * W + s_ax1[jb]])
              + s_wyh[ib] * (s_wxh[ja] * fc[s_ay0[ib] * W + s_ax0[ja]] + s_wxl[ja] * fc[s_ay0[ib] * W + s_ax1[ja]])
              + s_wyl[ib] * (s_wxh[ja] * fc[s_ay1[ib] * W + s_ax0[ja]] + s_wxl[ja] * fc[s_ay1[ib] * W + s_ax1[ja]])
              + s_wyh[ib] * (s_wxh[jb] * fc[s_ay0[ib] * W + s_ax0[jb]] + s_wxl[jb] * fc[s_ay0[ib] * W + s_ax1[jb]])
              + s_wyl[ib] * (s_wxh[jb] * fc[s_ay1[ib] * W + s_ax0[jb]] + s_wxl[jb] * fc[s_ay1[ib] * W + s_ax1[jb]]);
            ob[t] = acc * 0.25f;
        }
    }
}

extern "C" void kernel_launch(void* const* d_in, const int* in_sizes, int n_in,
                              void* d_out, int out_size, void* d_ws, size_t ws_size,
                              hipStream_t stream) {
    const float* f0    = (const float*)d_in[0];
    const float* f1    = (const float*)d_in[1];
    const float* f2    = (const float*)d_in[2];
    const float* f3    = (const float*)d_in[3];
    const float* boxes = (const float*)d_in[4];
    float*       outp  = (float*)d_out;

    const int R = out_size / (CCH * NBIN);   // 512
    roi_direct<<<dim3(R, NCHK), 256, 0, stream>>>(f0, f1, f2, f3, boxes, outp);
}